// Round 2
// baseline (183.947 us; speedup 1.0000x reference)
//
#include <hip/hip_runtime.h>
#include <math.h>

// NeRF two-pass renderer. One wave (64 lanes) per ray; 4 waves per block.
// B=65536 rays, KC=64 coarse, KF=64 fine, HID=32.
//
// R2 changes vs R1:
//  - coarse MLP outputs reused in fine pass (3 -> 2 MLP evals/lane); merged
//    (z, r, g, b, sigma) scattered through LDS by rank.
//  - layer-2 inner product via v_pk_fma_f32 (packed 2xfp32) with op_sel
//    broadcast of h; layer-1 via packed fma + scalar relu on halves.
//  - W2 staged in LDS (broadcast ds_read_b128 per j), keeping VGPRs low.

typedef float f32x2 __attribute__((ext_vector_type(2)));

__device__ __forceinline__ float fast_rcp(float x) { return __builtin_amdgcn_rcpf(x); }
__device__ __forceinline__ float fsigmoid(float x) { return fast_rcp(1.0f + __expf(-x)); }

__device__ __forceinline__ f32x2 pk_fma(f32x2 a, f32x2 b, f32x2 c) {
    f32x2 d;
    asm("v_pk_fma_f32 %0, %1, %2, %3" : "=v"(d) : "v"(a), "v"(b), "v"(c));
    return d;
}
// d = {a.lo, a.lo} * b + c
__device__ __forceinline__ f32x2 pk_fma_blo(f32x2 a, f32x2 b, f32x2 c) {
    f32x2 d;
    asm("v_pk_fma_f32 %0, %1, %2, %3 op_sel:[0,0,0] op_sel_hi:[0,1,1]"
        : "=v"(d) : "v"(a), "v"(b), "v"(c));
    return d;
}
// d = {a.hi, a.hi} * b + c
__device__ __forceinline__ f32x2 pk_fma_bhi(f32x2 a, f32x2 b, f32x2 c) {
    f32x2 d;
    asm("v_pk_fma_f32 %0, %1, %2, %3 op_sel:[1,0,0] op_sel_hi:[1,1,1]"
        : "=v"(d) : "v"(a), "v"(b), "v"(c));
    return d;
}

__global__ __launch_bounds__(256) void nerf_render(
    const float* __restrict__ rays,      // (B,8)  o(3) d(3) near far
    const float* __restrict__ u_coarse,  // (B,64)
    const float* __restrict__ u_fine,    // (B,64)
    const float* __restrict__ u_jitter,  // (B,64)
    const float* __restrict__ W1,        // (3,32)
    const float* __restrict__ b1,        // (32,)
    const float* __restrict__ W2,        // (32,4)
    const float* __restrict__ b2,        // (4,)
    float* __restrict__ out)             // (B,8)  rgb_f, depth_f, rgb_c, depth_c
{
    __shared__ float  acS[4][64];     // per wave: a[0..31], c[0..31]
    __shared__ float4 w2S[32];        // W2 rows, block-shared
    __shared__ float  mS[4][5][128];  // per wave merged: z, r, g, b, sigma

    const int lane = threadIdx.x & 63;
    const int wv   = threadIdx.x >> 6;
    const int ray  = (blockIdx.x << 2) + wv;

    const float* rp = rays + ray * 8;
    const float ox = rp[0], oy = rp[1], oz = rp[2];
    const float ddx = rp[3], ddy = rp[4], ddz = rp[5];
    const float nearv = rp[6], farv = rp[7];

    const float4 b2v = *reinterpret_cast<const float4*>(b2);

    if (threadIdx.x < 32) w2S[threadIdx.x] = reinterpret_cast<const float4*>(W2)[threadIdx.x];

    // cooperative a/c: lanes 0..31 -> a[j] = o@W1+b1, lanes 32..63 -> c[j] = d@W1
    {
        const int j = lane & 31;
        const float w0 = W1[j], w1 = W1[32 + j], w2 = W1[64 + j];
        const bool isA = lane < 32;
        const float px = isA ? ox : ddx;
        const float py = isA ? oy : ddy;
        const float pz = isA ? oz : ddz;
        const float bb = isA ? b1[j] : 0.0f;
        acS[wv][lane] = fmaf(px, w0, fmaf(py, w1, fmaf(pz, w2, bb)));
    }
    __syncthreads();

    const float* __restrict__ aw = &acS[wv][0];
    const float* __restrict__ cw = &acS[wv][32];

    // h = relu(a + z*c) (32); out4 = h @ W2 + b2; rgb=sigmoid, sigma raw
    auto mlp = [&](float z, float& rr, float& gg, float& bb_, float& sg) {
        f32x2 zz; zz.x = z; zz.y = z;
        f32x2 acc01; acc01.x = b2v.x; acc01.y = b2v.y;
        f32x2 acc23; acc23.x = b2v.z; acc23.y = b2v.w;
#pragma unroll
        for (int j = 0; j < 32; j += 4) {
            const float4 av4 = *reinterpret_cast<const float4*>(aw + j);
            const float4 cv4 = *reinterpret_cast<const float4*>(cw + j);
            f32x2 a01; a01.x = av4.x; a01.y = av4.y;
            f32x2 a23; a23.x = av4.z; a23.y = av4.w;
            f32x2 c01; c01.x = cv4.x; c01.y = cv4.y;
            f32x2 c23; c23.x = cv4.z; c23.y = cv4.w;
            f32x2 h01 = pk_fma(zz, c01, a01);
            f32x2 h23 = pk_fma(zz, c23, a23);
            h01.x = fmaxf(h01.x, 0.0f); h01.y = fmaxf(h01.y, 0.0f);
            h23.x = fmaxf(h23.x, 0.0f); h23.y = fmaxf(h23.y, 0.0f);
            {
                const float4 w4 = w2S[j + 0];
                f32x2 w01; w01.x = w4.x; w01.y = w4.y;
                f32x2 w23; w23.x = w4.z; w23.y = w4.w;
                acc01 = pk_fma_blo(h01, w01, acc01);
                acc23 = pk_fma_blo(h01, w23, acc23);
            }
            {
                const float4 w4 = w2S[j + 1];
                f32x2 w01; w01.x = w4.x; w01.y = w4.y;
                f32x2 w23; w23.x = w4.z; w23.y = w4.w;
                acc01 = pk_fma_bhi(h01, w01, acc01);
                acc23 = pk_fma_bhi(h01, w23, acc23);
            }
            {
                const float4 w4 = w2S[j + 2];
                f32x2 w01; w01.x = w4.x; w01.y = w4.y;
                f32x2 w23; w23.x = w4.z; w23.y = w4.w;
                acc01 = pk_fma_blo(h23, w01, acc01);
                acc23 = pk_fma_blo(h23, w23, acc23);
            }
            {
                const float4 w4 = w2S[j + 3];
                f32x2 w01; w01.x = w4.x; w01.y = w4.y;
                f32x2 w23; w23.x = w4.z; w23.y = w4.w;
                acc01 = pk_fma_bhi(h23, w01, acc01);
                acc23 = pk_fma_bhi(h23, w23, acc23);
            }
        }
        rr = fsigmoid(acc01.x); gg = fsigmoid(acc01.y);
        bb_ = fsigmoid(acc23.x); sg = acc23.y;
    };

    // ---------------- coarse pass ----------------
    const float uc = u_coarse[ray * 64 + lane];
    const float zsc = (float)lane * 0.015625f + uc * 0.015625f;  // bit-match ref
    const float zc = nearv * (1.0f - zsc) + farv * zsc;

    const float zcn = __shfl_down(zc, 1);
    const float deltac = (lane == 63) ? (farv - zc) : (zcn - zc);

    float cr_, cg_, cb_, csig;
    mlp(zc, cr_, cg_, cb_, csig);
    const float alphac = 1.0f - __expf(-deltac * fmaxf(csig, 0.0f));
    const float sc = 1.0f - alphac + 1e-10f;

    // exclusive prefix product -> transmittance
    float p = sc;
#pragma unroll
    for (int off = 1; off < 64; off <<= 1) {
        const float t = __shfl_up(p, off);
        if (lane >= off) p *= t;
    }
    float Tc = __shfl_up(p, 1);
    if (lane == 0) Tc = 1.0f;
    const float wc = alphac * Tc;

    float rc = wc * cr_, gc = wc * cg_, bc = wc * cb_, dc = wc * zc;
#pragma unroll
    for (int off = 32; off; off >>= 1) {
        rc += __shfl_xor(rc, off);
        gc += __shfl_xor(gc, off);
        bc += __shfl_xor(bc, off);
        dc += __shfl_xor(dc, off);
    }

    // ---------------- fine sampling (inverse CDF) ----------------
    const float wp = wc + 1e-5f;
    float tot = wp;
#pragma unroll
    for (int off = 32; off; off >>= 1) tot += __shfl_xor(tot, off);
    const float pdf = wp / tot;
    float cdf = pdf;  // inclusive prefix sum
#pragma unroll
    for (int off = 1; off < 64; off <<= 1) {
        const float t = __shfl_up(cdf, off);
        if (lane >= off) cdf += t;
    }

    const float uf = u_fine[ray * 64 + lane];
    // inds = #{k: cdf_incl[k] <= u} == searchsorted_right(cdf0, u) - 1, clamped
    int cnt = 0;
#pragma unroll
    for (int step = 64; step >= 1; step >>= 1) {
        const int idx = cnt + step - 1;
        const float v = __shfl(cdf, idx < 64 ? idx : 63);
        if (idx < 64 && v <= uf) cnt += step;
    }
    const float uj = u_jitter[ray * 64 + lane];
    const float zsf = ((float)cnt + uj) * 0.015625f;
    float zf = nearv * (1.0f - zsf) + farv * zsf;

    // ---------------- sort fine z (bitonic, 64 lanes) ----------------
#pragma unroll
    for (int k = 2; k <= 64; k <<= 1) {
#pragma unroll
        for (int j = k >> 1; j > 0; j >>= 1) {
            const float v = __shfl_xor(zf, j);
            const bool keepMin = (((lane & j) == 0) == ((lane & k) == 0));
            zf = keepMin ? fminf(zf, v) : fmaxf(zf, v);
        }
    }

    // fine MLP on sorted fine z (coarse outputs are reused, not recomputed)
    float fr_, fg_, fb_, fsig;
    mlp(zf, fr_, fg_, fb_, fsig);

    // ---------------- merge by rank ----------------
    // coarse element: pos = lane + #{fine < zc}  (strict: stable tie order)
    int cf = 0;
#pragma unroll
    for (int step = 64; step >= 1; step >>= 1) {
        const int idx = cf + step - 1;
        const float v = __shfl(zf, idx < 64 ? idx : 63);
        if (idx < 64 && v < zc) cf += step;
    }
    // fine element: pos = lane + #{coarse <= zf}
    int cc = 0;
#pragma unroll
    for (int step = 64; step >= 1; step >>= 1) {
        const int idx = cc + step - 1;
        const float v = __shfl(zc, idx < 64 ? idx : 63);
        if (idx < 64 && v <= zf) cc += step;
    }
    {
        const int pc = lane + cf;
        const int pf = lane + cc;
        mS[wv][0][pc] = zc;   mS[wv][0][pf] = zf;
        mS[wv][1][pc] = cr_;  mS[wv][1][pf] = fr_;
        mS[wv][2][pc] = cg_;  mS[wv][2][pf] = fg_;
        mS[wv][3][pc] = cb_;  mS[wv][3][pf] = fb_;
        mS[wv][4][pc] = csig; mS[wv][4][pf] = fsig;
    }
    __syncthreads();

    // ---------------- fine composite (2 samples / lane) ----------------
    const float2 zz2 = *reinterpret_cast<const float2*>(&mS[wv][0][2 * lane]);
    const float z0 = zz2.x, z1 = zz2.y;
    const float z2n = mS[wv][0][(2 * lane + 2) & 127];
    const float2 rr2 = *reinterpret_cast<const float2*>(&mS[wv][1][2 * lane]);
    const float2 gg2 = *reinterpret_cast<const float2*>(&mS[wv][2][2 * lane]);
    const float2 bb2 = *reinterpret_cast<const float2*>(&mS[wv][3][2 * lane]);
    const float2 ss2 = *reinterpret_cast<const float2*>(&mS[wv][4][2 * lane]);

    const float d0 = z1 - z0;
    const float d1 = (lane == 63) ? (farv - z1) : (z2n - z1);

    const float al0 = 1.0f - __expf(-d0 * fmaxf(ss2.x, 0.0f));
    const float al1 = 1.0f - __expf(-d1 * fmaxf(ss2.y, 0.0f));
    const float t0 = 1.0f - al0 + 1e-10f;
    const float t1 = 1.0f - al1 + 1e-10f;

    float pp = t0 * t1;  // pair product, exclusive scan across lanes
#pragma unroll
    for (int off = 1; off < 64; off <<= 1) {
        const float t = __shfl_up(pp, off);
        if (lane >= off) pp *= t;
    }
    float Te = __shfl_up(pp, 1);
    if (lane == 0) Te = 1.0f;
    const float w0 = al0 * Te;
    const float w1 = al1 * (Te * t0);

    float fr = fmaf(w0, rr2.x, w1 * rr2.y);
    float fg = fmaf(w0, gg2.x, w1 * gg2.y);
    float fb = fmaf(w0, bb2.x, w1 * bb2.y);
    float fd = fmaf(w0, z0, w1 * z1);
#pragma unroll
    for (int off = 32; off; off >>= 1) {
        fr += __shfl_xor(fr, off);
        fg += __shfl_xor(fg, off);
        fb += __shfl_xor(fb, off);
        fd += __shfl_xor(fd, off);
    }

    if (lane == 0) {
        float4* op = reinterpret_cast<float4*>(out + ray * 8);
        op[0] = make_float4(fr, fg, fb, fd);
        op[1] = make_float4(rc, gc, bc, dc);
    }
}

extern "C" void kernel_launch(void* const* d_in, const int* in_sizes, int n_in,
                              void* d_out, int out_size, void* d_ws, size_t ws_size,
                              hipStream_t stream) {
    const float* rays     = (const float*)d_in[0];
    const float* u_coarse = (const float*)d_in[1];
    const float* u_fine   = (const float*)d_in[2];
    const float* u_jitter = (const float*)d_in[3];
    const float* W1       = (const float*)d_in[4];
    const float* b1       = (const float*)d_in[5];
    const float* W2       = (const float*)d_in[6];
    const float* b2       = (const float*)d_in[7];
    float* out = (float*)d_out;

    const int B = in_sizes[0] / 8;          // 65536
    dim3 grid(B / 4), block(256);           // one wave per ray, 4 waves/block
    hipLaunchKernelGGL(nerf_render, grid, block, 0, stream,
                       rays, u_coarse, u_fine, u_jitter, W1, b1, W2, b2, out);
}

// Round 3
// 136.062 us; speedup vs baseline: 1.3519x; 1.3519x over previous
//
#include <hip/hip_runtime.h>
#include <math.h>

// NeRF two-pass renderer. One wave (64 lanes) per ray; 4 waves per block.
// B=65536 rays, KC=64 coarse, KF=64 fine, HID=32.
//
// R3 = R1 codegen + R2's coarse-output reuse:
//  - layer-1 factorization: (o+z*d)@W1+b1 = a + z*c; a,c per-ray in LDS.
//  - W2/b2 read via uniform global pointer with constant offsets -> compiler
//    s_loads into SGPRs (R1 showed VGPR=40/SGPR=112 with this form).
//  - coarse MLP outputs reused in fine pass (2 MLP evals/lane, not 3);
//    merged (z,r,g,b,sigma) scattered through LDS by rank.

__device__ __forceinline__ float fast_rcp(float x) { return __builtin_amdgcn_rcpf(x); }
__device__ __forceinline__ float fsigmoid(float x) { return fast_rcp(1.0f + __expf(-x)); }

__global__ __launch_bounds__(256) void nerf_render(
    const float* __restrict__ rays,      // (B,8)  o(3) d(3) near far
    const float* __restrict__ u_coarse,  // (B,64)
    const float* __restrict__ u_fine,    // (B,64)
    const float* __restrict__ u_jitter,  // (B,64)
    const float* __restrict__ W1,        // (3,32)
    const float* __restrict__ b1,        // (32,)
    const float* __restrict__ W2,        // (32,4)
    const float* __restrict__ b2,        // (4,)
    float* __restrict__ out)             // (B,8)  rgb_f, depth_f, rgb_c, depth_c
{
    __shared__ float acS[4][64];     // per wave: a[0..31], c[0..31]
    __shared__ float mS[4][5][128];  // per wave merged: z, r, g, b, sigma

    const int lane = threadIdx.x & 63;
    const int wv   = threadIdx.x >> 6;
    const int ray  = (blockIdx.x << 2) + wv;

    const float* rp = rays + ray * 8;
    const float ox = rp[0], oy = rp[1], oz = rp[2];
    const float ddx = rp[3], ddy = rp[4], ddz = rp[5];
    const float nearv = rp[6], farv = rp[7];

    // cooperative a/c: lanes 0..31 -> a[j] = o@W1+b1, lanes 32..63 -> c[j] = d@W1
    {
        const int j = lane & 31;
        const float w0 = W1[j], w1 = W1[32 + j], w2 = W1[64 + j];
        const bool isA = lane < 32;
        const float px = isA ? ox : ddx;
        const float py = isA ? oy : ddy;
        const float pz = isA ? oz : ddz;
        const float bb = isA ? b1[j] : 0.0f;
        acS[wv][lane] = fmaf(px, w0, fmaf(py, w1, fmaf(pz, w2, bb)));
    }
    __syncthreads();

    const float* __restrict__ aw = &acS[wv][0];
    const float* __restrict__ cw = &acS[wv][32];

    // h = relu(a + z*c) (32); out4 = h @ W2 + b2; rgb=sigmoid, sigma raw.
    // W2/b2 indexed with compile-time-constant offsets on the uniform global
    // pointer -> scalar loads / SGPR operands (one SGPR per v_fma is legal).
    auto mlp = [&](float z, float& rr, float& gg, float& bb_, float& sg) {
        float a0 = b2[0], a1 = b2[1], a2 = b2[2], a3 = b2[3];
#pragma unroll
        for (int j = 0; j < 32; j += 4) {
            const float4 av = *reinterpret_cast<const float4*>(aw + j);
            const float4 cv = *reinterpret_cast<const float4*>(cw + j);
            float h;
            h = fmaxf(fmaf(z, cv.x, av.x), 0.0f);
            a0 = fmaf(h, W2[(j+0)*4+0], a0); a1 = fmaf(h, W2[(j+0)*4+1], a1);
            a2 = fmaf(h, W2[(j+0)*4+2], a2); a3 = fmaf(h, W2[(j+0)*4+3], a3);
            h = fmaxf(fmaf(z, cv.y, av.y), 0.0f);
            a0 = fmaf(h, W2[(j+1)*4+0], a0); a1 = fmaf(h, W2[(j+1)*4+1], a1);
            a2 = fmaf(h, W2[(j+1)*4+2], a2); a3 = fmaf(h, W2[(j+1)*4+3], a3);
            h = fmaxf(fmaf(z, cv.z, av.z), 0.0f);
            a0 = fmaf(h, W2[(j+2)*4+0], a0); a1 = fmaf(h, W2[(j+2)*4+1], a1);
            a2 = fmaf(h, W2[(j+2)*4+2], a2); a3 = fmaf(h, W2[(j+2)*4+3], a3);
            h = fmaxf(fmaf(z, cv.w, av.w), 0.0f);
            a0 = fmaf(h, W2[(j+3)*4+0], a0); a1 = fmaf(h, W2[(j+3)*4+1], a1);
            a2 = fmaf(h, W2[(j+3)*4+2], a2); a3 = fmaf(h, W2[(j+3)*4+3], a3);
        }
        rr = fsigmoid(a0); gg = fsigmoid(a1); bb_ = fsigmoid(a2); sg = a3;
    };

    // ---------------- coarse pass ----------------
    const float uc = u_coarse[ray * 64 + lane];
    const float zsc = (float)lane * 0.015625f + uc * 0.015625f;  // bit-match ref
    const float zc = nearv * (1.0f - zsc) + farv * zsc;

    const float zcn = __shfl_down(zc, 1);
    const float deltac = (lane == 63) ? (farv - zc) : (zcn - zc);

    float cr_, cg_, cb_, csig;
    mlp(zc, cr_, cg_, cb_, csig);
    const float alphac = 1.0f - __expf(-deltac * fmaxf(csig, 0.0f));
    const float sc = 1.0f - alphac + 1e-10f;

    // exclusive prefix product -> transmittance
    float p = sc;
#pragma unroll
    for (int off = 1; off < 64; off <<= 1) {
        const float t = __shfl_up(p, off);
        if (lane >= off) p *= t;
    }
    float Tc = __shfl_up(p, 1);
    if (lane == 0) Tc = 1.0f;
    const float wc = alphac * Tc;

    float rc = wc * cr_, gc = wc * cg_, bc = wc * cb_, dc = wc * zc;
#pragma unroll
    for (int off = 32; off; off >>= 1) {
        rc += __shfl_xor(rc, off);
        gc += __shfl_xor(gc, off);
        bc += __shfl_xor(bc, off);
        dc += __shfl_xor(dc, off);
    }

    // ---------------- fine sampling (inverse CDF) ----------------
    const float wp = wc + 1e-5f;
    float tot = wp;
#pragma unroll
    for (int off = 32; off; off >>= 1) tot += __shfl_xor(tot, off);
    const float pdf = wp / tot;
    float cdf = pdf;  // inclusive prefix sum
#pragma unroll
    for (int off = 1; off < 64; off <<= 1) {
        const float t = __shfl_up(cdf, off);
        if (lane >= off) cdf += t;
    }

    const float uf = u_fine[ray * 64 + lane];
    // inds = #{k: cdf_incl[k] <= u} == searchsorted_right(cdf0, u) - 1, clamped
    int cnt = 0;
#pragma unroll
    for (int step = 64; step >= 1; step >>= 1) {
        const int idx = cnt + step - 1;
        const float v = __shfl(cdf, idx < 64 ? idx : 63);
        if (idx < 64 && v <= uf) cnt += step;
    }
    const float uj = u_jitter[ray * 64 + lane];
    const float zsf = ((float)cnt + uj) * 0.015625f;
    float zf = nearv * (1.0f - zsf) + farv * zsf;

    // ---------------- sort fine z (bitonic, 64 lanes) ----------------
#pragma unroll
    for (int k = 2; k <= 64; k <<= 1) {
#pragma unroll
        for (int j = k >> 1; j > 0; j >>= 1) {
            const float v = __shfl_xor(zf, j);
            const bool keepMin = (((lane & j) == 0) == ((lane & k) == 0));
            zf = keepMin ? fminf(zf, v) : fmaxf(zf, v);
        }
    }

    // fine MLP on sorted fine z (coarse outputs reused, not recomputed)
    float fr_, fg_, fb_, fsig;
    mlp(zf, fr_, fg_, fb_, fsig);

    // ---------------- merge by rank ----------------
    // coarse element: pos = lane + #{fine < zc}  (strict: stable tie order)
    int cf = 0;
#pragma unroll
    for (int step = 64; step >= 1; step >>= 1) {
        const int idx = cf + step - 1;
        const float v = __shfl(zf, idx < 64 ? idx : 63);
        if (idx < 64 && v < zc) cf += step;
    }
    // fine element: pos = lane + #{coarse <= zf}
    int cc = 0;
#pragma unroll
    for (int step = 64; step >= 1; step >>= 1) {
        const int idx = cc + step - 1;
        const float v = __shfl(zc, idx < 64 ? idx : 63);
        if (idx < 64 && v <= zf) cc += step;
    }
    {
        const int pc = lane + cf;
        const int pf = lane + cc;
        mS[wv][0][pc] = zc;   mS[wv][0][pf] = zf;
        mS[wv][1][pc] = cr_;  mS[wv][1][pf] = fr_;
        mS[wv][2][pc] = cg_;  mS[wv][2][pf] = fg_;
        mS[wv][3][pc] = cb_;  mS[wv][3][pf] = fb_;
        mS[wv][4][pc] = csig; mS[wv][4][pf] = fsig;
    }
    __syncthreads();

    // ---------------- fine composite (2 samples / lane) ----------------
    const float2 zz2 = *reinterpret_cast<const float2*>(&mS[wv][0][2 * lane]);
    const float z0 = zz2.x, z1 = zz2.y;
    const float z2n = mS[wv][0][(2 * lane + 2) & 127];
    const float2 rr2 = *reinterpret_cast<const float2*>(&mS[wv][1][2 * lane]);
    const float2 gg2 = *reinterpret_cast<const float2*>(&mS[wv][2][2 * lane]);
    const float2 bb2 = *reinterpret_cast<const float2*>(&mS[wv][3][2 * lane]);
    const float2 ss2 = *reinterpret_cast<const float2*>(&mS[wv][4][2 * lane]);

    const float d0 = z1 - z0;
    const float d1 = (lane == 63) ? (farv - z1) : (z2n - z1);

    const float al0 = 1.0f - __expf(-d0 * fmaxf(ss2.x, 0.0f));
    const float al1 = 1.0f - __expf(-d1 * fmaxf(ss2.y, 0.0f));
    const float t0 = 1.0f - al0 + 1e-10f;
    const float t1 = 1.0f - al1 + 1e-10f;

    float pp = t0 * t1;  // pair product, exclusive scan across lanes
#pragma unroll
    for (int off = 1; off < 64; off <<= 1) {
        const float t = __shfl_up(pp, off);
        if (lane >= off) pp *= t;
    }
    float Te = __shfl_up(pp, 1);
    if (lane == 0) Te = 1.0f;
    const float w0 = al0 * Te;
    const float w1 = al1 * (Te * t0);

    float fr = fmaf(w0, rr2.x, w1 * rr2.y);
    float fg = fmaf(w0, gg2.x, w1 * gg2.y);
    float fb = fmaf(w0, bb2.x, w1 * bb2.y);
    float fd = fmaf(w0, z0, w1 * z1);
#pragma unroll
    for (int off = 32; off; off >>= 1) {
        fr += __shfl_xor(fr, off);
        fg += __shfl_xor(fg, off);
        fb += __shfl_xor(fb, off);
        fd += __shfl_xor(fd, off);
    }

    if (lane == 0) {
        float4* op = reinterpret_cast<float4*>(out + ray * 8);
        op[0] = make_float4(fr, fg, fb, fd);
        op[1] = make_float4(rc, gc, bc, dc);
    }
}

extern "C" void kernel_launch(void* const* d_in, const int* in_sizes, int n_in,
                              void* d_out, int out_size, void* d_ws, size_t ws_size,
                              hipStream_t stream) {
    const float* rays     = (const float*)d_in[0];
    const float* u_coarse = (const float*)d_in[1];
    const float* u_fine   = (const float*)d_in[2];
    const float* u_jitter = (const float*)d_in[3];
    const float* W1       = (const float*)d_in[4];
    const float* b1       = (const float*)d_in[5];
    const float* W2       = (const float*)d_in[6];
    const float* b2       = (const float*)d_in[7];
    float* out = (float*)d_out;

    const int B = in_sizes[0] / 8;          // 65536
    dim3 grid(B / 4), block(256);           // one wave per ray, 4 waves/block
    hipLaunchKernelGGL(nerf_render, grid, block, 0, stream,
                       rays, u_coarse, u_fine, u_jitter, W1, b1, W2, b2, out);
}

// Round 4
// 124.298 us; speedup vs baseline: 1.4799x; 1.0946x over previous
//
#include <hip/hip_runtime.h>
#include <math.h>

// NeRF two-pass renderer. One wave (64 lanes) per ray; 4 waves per block.
// B=65536 rays, KC=64 coarse, KF=64 fine, HID=32.
//
// R4 = R3 + compiler-packed fp32 MLP + cdf-normalization removal:
//  - layer-1 factorization: (o+z*d)@W1+b1 = a + z*c; a,c per-ray in LDS.
//  - MLP math in float2 ext-vectors via __builtin_elementwise_fma/max so the
//    compiler can select v_pk_fma_f32 / v_pk_max_f32 (VOP3P) with op_sel
//    splats; W2/b2 pairs from the uniform pointer -> s_load_dwordx2 pairs.
//    Per-channel accumulation order unchanged -> bit-identical to R3.
//  - coarse MLP outputs reused in fine pass (2 MLP evals/lane, not 3).
//  - fine sampling: scan unnormalized weights; tot = readlane(cdf,63);
//    searchsorted compares cdf <= u*tot (drops 6-step reduce + divide).

typedef float f32x2 __attribute__((ext_vector_type(2)));

__device__ __forceinline__ float fast_rcp(float x) { return __builtin_amdgcn_rcpf(x); }
__device__ __forceinline__ float fsigmoid(float x) { return fast_rcp(1.0f + __expf(-x)); }

__device__ __forceinline__ f32x2 splat_lo(f32x2 v) { return __builtin_shufflevector(v, v, 0, 0); }
__device__ __forceinline__ f32x2 splat_hi(f32x2 v) { return __builtin_shufflevector(v, v, 1, 1); }

__global__ __launch_bounds__(256) void nerf_render(
    const float* __restrict__ rays,      // (B,8)  o(3) d(3) near far
    const float* __restrict__ u_coarse,  // (B,64)
    const float* __restrict__ u_fine,    // (B,64)
    const float* __restrict__ u_jitter,  // (B,64)
    const float* __restrict__ W1,        // (3,32)
    const float* __restrict__ b1,        // (32,)
    const float* __restrict__ W2,        // (32,4)
    const float* __restrict__ b2,        // (4,)
    float* __restrict__ out)             // (B,8)  rgb_f, depth_f, rgb_c, depth_c
{
    __shared__ float acS[4][64];     // per wave: a[0..31], c[0..31]
    __shared__ float mS[4][5][128];  // per wave merged: z, r, g, b, sigma

    const int lane = threadIdx.x & 63;
    const int wv   = threadIdx.x >> 6;
    const int ray  = (blockIdx.x << 2) + wv;

    const float* rp = rays + ray * 8;
    const float ox = rp[0], oy = rp[1], oz = rp[2];
    const float ddx = rp[3], ddy = rp[4], ddz = rp[5];
    const float nearv = rp[6], farv = rp[7];

    // cooperative a/c: lanes 0..31 -> a[j] = o@W1+b1, lanes 32..63 -> c[j] = d@W1
    {
        const int j = lane & 31;
        const float w0 = W1[j], w1 = W1[32 + j], w2 = W1[64 + j];
        const bool isA = lane < 32;
        const float px = isA ? ox : ddx;
        const float py = isA ? oy : ddy;
        const float pz = isA ? oz : ddz;
        const float bb = isA ? b1[j] : 0.0f;
        acS[wv][lane] = fmaf(px, w0, fmaf(py, w1, fmaf(pz, w2, bb)));
    }
    __syncthreads();

    const float* __restrict__ aw = &acS[wv][0];
    const float* __restrict__ cw = &acS[wv][32];

    // h = relu(a + z*c) (32); out4 = h @ W2 + b2; rgb=sigmoid, sigma raw.
    auto mlp = [&](float z, float& rr, float& gg, float& bb_, float& sg) {
        const f32x2 zz = {z, z};
        const f32x2 zero2 = {0.0f, 0.0f};
        f32x2 acc01 = *reinterpret_cast<const f32x2*>(b2);
        f32x2 acc23 = *reinterpret_cast<const f32x2*>(b2 + 2);
#pragma unroll
        for (int j = 0; j < 32; j += 4) {
            const f32x2 a01 = *reinterpret_cast<const f32x2*>(aw + j);
            const f32x2 a23 = *reinterpret_cast<const f32x2*>(aw + j + 2);
            const f32x2 c01 = *reinterpret_cast<const f32x2*>(cw + j);
            const f32x2 c23 = *reinterpret_cast<const f32x2*>(cw + j + 2);
            f32x2 h01 = __builtin_elementwise_fma(zz, c01, a01);
            f32x2 h23 = __builtin_elementwise_fma(zz, c23, a23);
            h01 = __builtin_elementwise_max(h01, zero2);
            h23 = __builtin_elementwise_max(h23, zero2);
            {
                const f32x2 wA = *reinterpret_cast<const f32x2*>(W2 + (j + 0) * 4);
                const f32x2 wB = *reinterpret_cast<const f32x2*>(W2 + (j + 0) * 4 + 2);
                const f32x2 hs = splat_lo(h01);
                acc01 = __builtin_elementwise_fma(hs, wA, acc01);
                acc23 = __builtin_elementwise_fma(hs, wB, acc23);
            }
            {
                const f32x2 wA = *reinterpret_cast<const f32x2*>(W2 + (j + 1) * 4);
                const f32x2 wB = *reinterpret_cast<const f32x2*>(W2 + (j + 1) * 4 + 2);
                const f32x2 hs = splat_hi(h01);
                acc01 = __builtin_elementwise_fma(hs, wA, acc01);
                acc23 = __builtin_elementwise_fma(hs, wB, acc23);
            }
            {
                const f32x2 wA = *reinterpret_cast<const f32x2*>(W2 + (j + 2) * 4);
                const f32x2 wB = *reinterpret_cast<const f32x2*>(W2 + (j + 2) * 4 + 2);
                const f32x2 hs = splat_lo(h23);
                acc01 = __builtin_elementwise_fma(hs, wA, acc01);
                acc23 = __builtin_elementwise_fma(hs, wB, acc23);
            }
            {
                const f32x2 wA = *reinterpret_cast<const f32x2*>(W2 + (j + 3) * 4);
                const f32x2 wB = *reinterpret_cast<const f32x2*>(W2 + (j + 3) * 4 + 2);
                const f32x2 hs = splat_hi(h23);
                acc01 = __builtin_elementwise_fma(hs, wA, acc01);
                acc23 = __builtin_elementwise_fma(hs, wB, acc23);
            }
        }
        rr = fsigmoid(acc01.x); gg = fsigmoid(acc01.y);
        bb_ = fsigmoid(acc23.x); sg = acc23.y;
    };

    // ---------------- coarse pass ----------------
    const float uc = u_coarse[ray * 64 + lane];
    const float zsc = (float)lane * 0.015625f + uc * 0.015625f;  // bit-match ref
    const float zc = nearv * (1.0f - zsc) + farv * zsc;

    const float zcn = __shfl_down(zc, 1);
    const float deltac = (lane == 63) ? (farv - zc) : (zcn - zc);

    float cr_, cg_, cb_, csig;
    mlp(zc, cr_, cg_, cb_, csig);
    const float alphac = 1.0f - __expf(-deltac * fmaxf(csig, 0.0f));
    const float sc = 1.0f - alphac + 1e-10f;

    // exclusive prefix product -> transmittance
    float p = sc;
#pragma unroll
    for (int off = 1; off < 64; off <<= 1) {
        const float t = __shfl_up(p, off);
        if (lane >= off) p *= t;
    }
    float Tc = __shfl_up(p, 1);
    if (lane == 0) Tc = 1.0f;
    const float wc = alphac * Tc;

    float rc = wc * cr_, gc = wc * cg_, bc = wc * cb_, dc = wc * zc;
#pragma unroll
    for (int off = 32; off; off >>= 1) {
        rc += __shfl_xor(rc, off);
        gc += __shfl_xor(gc, off);
        bc += __shfl_xor(bc, off);
        dc += __shfl_xor(dc, off);
    }

    // ---------------- fine sampling (inverse CDF, unnormalized) ----------------
    const float wp = wc + 1e-5f;
    float cdf = wp;  // inclusive prefix sum of unnormalized weights
#pragma unroll
    for (int off = 1; off < 64; off <<= 1) {
        const float t = __shfl_up(cdf, off);
        if (lane >= off) cdf += t;
    }
    const float tot = __int_as_float(__builtin_amdgcn_readlane(__float_as_int(cdf), 63));

    const float uf = u_fine[ray * 64 + lane] * tot;  // compare in unnormalized space
    // inds = #{k: cdf_incl[k] <= u} == searchsorted_right(cdf0, u) - 1, clamped
    int cnt = 0;
#pragma unroll
    for (int step = 64; step >= 1; step >>= 1) {
        const int idx = cnt + step - 1;
        const float v = __shfl(cdf, idx < 64 ? idx : 63);
        if (idx < 64 && v <= uf) cnt += step;
    }
    const float uj = u_jitter[ray * 64 + lane];
    const float zsf = ((float)cnt + uj) * 0.015625f;
    float zf = nearv * (1.0f - zsf) + farv * zsf;

    // ---------------- sort fine z (bitonic, 64 lanes) ----------------
#pragma unroll
    for (int k = 2; k <= 64; k <<= 1) {
#pragma unroll
        for (int j = k >> 1; j > 0; j >>= 1) {
            const float v = __shfl_xor(zf, j);
            const bool keepMin = (((lane & j) == 0) == ((lane & k) == 0));
            zf = keepMin ? fminf(zf, v) : fmaxf(zf, v);
        }
    }

    // fine MLP on sorted fine z (coarse outputs reused, not recomputed)
    float fr_, fg_, fb_, fsig;
    mlp(zf, fr_, fg_, fb_, fsig);

    // ---------------- merge by rank ----------------
    // coarse element: pos = lane + #{fine < zc}  (strict: stable tie order)
    int cf = 0;
#pragma unroll
    for (int step = 64; step >= 1; step >>= 1) {
        const int idx = cf + step - 1;
        const float v = __shfl(zf, idx < 64 ? idx : 63);
        if (idx < 64 && v < zc) cf += step;
    }
    // fine element: pos = lane + #{coarse <= zf}
    int cc = 0;
#pragma unroll
    for (int step = 64; step >= 1; step >>= 1) {
        const int idx = cc + step - 1;
        const float v = __shfl(zc, idx < 64 ? idx : 63);
        if (idx < 64 && v <= zf) cc += step;
    }
    {
        const int pc = lane + cf;
        const int pf = lane + cc;
        mS[wv][0][pc] = zc;   mS[wv][0][pf] = zf;
        mS[wv][1][pc] = cr_;  mS[wv][1][pf] = fr_;
        mS[wv][2][pc] = cg_;  mS[wv][2][pf] = fg_;
        mS[wv][3][pc] = cb_;  mS[wv][3][pf] = fb_;
        mS[wv][4][pc] = csig; mS[wv][4][pf] = fsig;
    }
    __syncthreads();

    // ---------------- fine composite (2 samples / lane) ----------------
    const float2 zz2 = *reinterpret_cast<const float2*>(&mS[wv][0][2 * lane]);
    const float z0 = zz2.x, z1 = zz2.y;
    const float z2n = mS[wv][0][(2 * lane + 2) & 127];
    const float2 rr2 = *reinterpret_cast<const float2*>(&mS[wv][1][2 * lane]);
    const float2 gg2 = *reinterpret_cast<const float2*>(&mS[wv][2][2 * lane]);
    const float2 bb2 = *reinterpret_cast<const float2*>(&mS[wv][3][2 * lane]);
    const float2 ss2 = *reinterpret_cast<const float2*>(&mS[wv][4][2 * lane]);

    const float d0 = z1 - z0;
    const float d1 = (lane == 63) ? (farv - z1) : (z2n - z1);

    const float al0 = 1.0f - __expf(-d0 * fmaxf(ss2.x, 0.0f));
    const float al1 = 1.0f - __expf(-d1 * fmaxf(ss2.y, 0.0f));
    const float t0 = 1.0f - al0 + 1e-10f;
    const float t1 = 1.0f - al1 + 1e-10f;

    float pp = t0 * t1;  // pair product, exclusive scan across lanes
#pragma unroll
    for (int off = 1; off < 64; off <<= 1) {
        const float t = __shfl_up(pp, off);
        if (lane >= off) pp *= t;
    }
    float Te = __shfl_up(pp, 1);
    if (lane == 0) Te = 1.0f;
    const float w0 = al0 * Te;
    const float w1 = al1 * (Te * t0);

    float fr = fmaf(w0, rr2.x, w1 * rr2.y);
    float fg = fmaf(w0, gg2.x, w1 * gg2.y);
    float fb = fmaf(w0, bb2.x, w1 * bb2.y);
    float fd = fmaf(w0, z0, w1 * z1);
#pragma unroll
    for (int off = 32; off; off >>= 1) {
        fr += __shfl_xor(fr, off);
        fg += __shfl_xor(fg, off);
        fb += __shfl_xor(fb, off);
        fd += __shfl_xor(fd, off);
    }

    if (lane == 0) {
        float4* op = reinterpret_cast<float4*>(out + ray * 8);
        op[0] = make_float4(fr, fg, fb, fd);
        op[1] = make_float4(rc, gc, bc, dc);
    }
}

extern "C" void kernel_launch(void* const* d_in, const int* in_sizes, int n_in,
                              void* d_out, int out_size, void* d_ws, size_t ws_size,
                              hipStream_t stream) {
    const float* rays     = (const float*)d_in[0];
    const float* u_coarse = (const float*)d_in[1];
    const float* u_fine   = (const float*)d_in[2];
    const float* u_jitter = (const float*)d_in[3];
    const float* W1       = (const float*)d_in[4];
    const float* b1       = (const float*)d_in[5];
    const float* W2       = (const float*)d_in[6];
    const float* b2       = (const float*)d_in[7];
    float* out = (float*)d_out;

    const int B = in_sizes[0] / 8;          // 65536
    dim3 grid(B / 4), block(256);           // one wave per ray, 4 waves/block
    hipLaunchKernelGGL(nerf_render, grid, block, 0, stream,
                       rays, u_coarse, u_fine, u_jitter, W1, b1, W2, b2, out);
}

// Round 5
// 114.892 us; speedup vs baseline: 1.6010x; 1.0819x over previous
//
#include <hip/hip_runtime.h>
#include <math.h>

// NeRF two-pass renderer. One wave (64 lanes) per ray; 4 waves per block.
// B=65536 rays, KC=64 coarse, KF=64 fine, HID=32.
//
// R5 = R4 + DPP cross-lane (scans/reductions/bitonic-low-stages on VALU):
//  - inclusive scans + reduce-to-lane63 via row_shr:1/2/4/8 + row_bcast15/31
//    (documented GCN wave64 idiom), old=identity, masks 0xa/0xc.
//  - bitonic stages j=1,2 via quad_perm DPP; j>=4 stay ds_swizzle.
//  - output writes from lane 63 (reduction lands there).
//  - everything else as R4 (packed fp32 MLP, coarse-output reuse,
//    unnormalized cdf searchsorted).

typedef float f32x2 __attribute__((ext_vector_type(2)));

__device__ __forceinline__ float fast_rcp(float x) { return __builtin_amdgcn_rcpf(x); }
__device__ __forceinline__ float fsigmoid(float x) { return fast_rcp(1.0f + __expf(-x)); }

__device__ __forceinline__ f32x2 splat_lo(f32x2 v) { return __builtin_shufflevector(v, v, 0, 0); }
__device__ __forceinline__ f32x2 splat_hi(f32x2 v) { return __builtin_shufflevector(v, v, 1, 1); }

// DPP move: result = valid(src lane) ? shuffled x : oldv   (bound_ctrl=0)
template <int CTRL, int RMASK>
__device__ __forceinline__ float dpp_f(float x, float oldv) {
    return __int_as_float(__builtin_amdgcn_update_dpp(
        __float_as_int(oldv), __float_as_int(x), CTRL, RMASK, 0xf, false));
}

// inclusive multiply-scan over 64 lanes (lane i = prod_{j<=i})
__device__ __forceinline__ float scan_mul(float x) {
    x *= dpp_f<0x111, 0xf>(x, 1.0f);  // row_shr:1
    x *= dpp_f<0x112, 0xf>(x, 1.0f);  // row_shr:2
    x *= dpp_f<0x114, 0xf>(x, 1.0f);  // row_shr:4
    x *= dpp_f<0x118, 0xf>(x, 1.0f);  // row_shr:8
    x *= dpp_f<0x142, 0xa>(x, 1.0f);  // row_bcast:15 -> rows 1,3
    x *= dpp_f<0x143, 0xc>(x, 1.0f);  // row_bcast:31 -> rows 2,3
    return x;
}
// inclusive add-scan over 64 lanes; lane 63 holds the full sum
__device__ __forceinline__ float scan_add(float x) {
    x += dpp_f<0x111, 0xf>(x, 0.0f);
    x += dpp_f<0x112, 0xf>(x, 0.0f);
    x += dpp_f<0x114, 0xf>(x, 0.0f);
    x += dpp_f<0x118, 0xf>(x, 0.0f);
    x += dpp_f<0x142, 0xa>(x, 0.0f);
    x += dpp_f<0x143, 0xc>(x, 0.0f);
    return x;
}

__global__ __launch_bounds__(256) void nerf_render(
    const float* __restrict__ rays,      // (B,8)  o(3) d(3) near far
    const float* __restrict__ u_coarse,  // (B,64)
    const float* __restrict__ u_fine,    // (B,64)
    const float* __restrict__ u_jitter,  // (B,64)
    const float* __restrict__ W1,        // (3,32)
    const float* __restrict__ b1,        // (32,)
    const float* __restrict__ W2,        // (32,4)
    const float* __restrict__ b2,        // (4,)
    float* __restrict__ out)             // (B,8)  rgb_f, depth_f, rgb_c, depth_c
{
    __shared__ float acS[4][64];     // per wave: a[0..31], c[0..31]
    __shared__ float mS[4][5][128];  // per wave merged: z, r, g, b, sigma

    const int lane = threadIdx.x & 63;
    const int wv   = threadIdx.x >> 6;
    const int ray  = (blockIdx.x << 2) + wv;

    const float* rp = rays + ray * 8;
    const float ox = rp[0], oy = rp[1], oz = rp[2];
    const float ddx = rp[3], ddy = rp[4], ddz = rp[5];
    const float nearv = rp[6], farv = rp[7];

    // cooperative a/c: lanes 0..31 -> a[j] = o@W1+b1, lanes 32..63 -> c[j] = d@W1
    {
        const int j = lane & 31;
        const float w0 = W1[j], w1 = W1[32 + j], w2 = W1[64 + j];
        const bool isA = lane < 32;
        const float px = isA ? ox : ddx;
        const float py = isA ? oy : ddy;
        const float pz = isA ? oz : ddz;
        const float bb = isA ? b1[j] : 0.0f;
        acS[wv][lane] = fmaf(px, w0, fmaf(py, w1, fmaf(pz, w2, bb)));
    }
    __syncthreads();

    const float* __restrict__ aw = &acS[wv][0];
    const float* __restrict__ cw = &acS[wv][32];

    // h = relu(a + z*c) (32); out4 = h @ W2 + b2; rgb=sigmoid, sigma raw.
    auto mlp = [&](float z, float& rr, float& gg, float& bb_, float& sg) {
        const f32x2 zz = {z, z};
        const f32x2 zero2 = {0.0f, 0.0f};
        f32x2 acc01 = *reinterpret_cast<const f32x2*>(b2);
        f32x2 acc23 = *reinterpret_cast<const f32x2*>(b2 + 2);
#pragma unroll
        for (int j = 0; j < 32; j += 4) {
            const f32x2 a01 = *reinterpret_cast<const f32x2*>(aw + j);
            const f32x2 a23 = *reinterpret_cast<const f32x2*>(aw + j + 2);
            const f32x2 c01 = *reinterpret_cast<const f32x2*>(cw + j);
            const f32x2 c23 = *reinterpret_cast<const f32x2*>(cw + j + 2);
            f32x2 h01 = __builtin_elementwise_fma(zz, c01, a01);
            f32x2 h23 = __builtin_elementwise_fma(zz, c23, a23);
            h01 = __builtin_elementwise_max(h01, zero2);
            h23 = __builtin_elementwise_max(h23, zero2);
            {
                const f32x2 wA = *reinterpret_cast<const f32x2*>(W2 + (j + 0) * 4);
                const f32x2 wB = *reinterpret_cast<const f32x2*>(W2 + (j + 0) * 4 + 2);
                const f32x2 hs = splat_lo(h01);
                acc01 = __builtin_elementwise_fma(hs, wA, acc01);
                acc23 = __builtin_elementwise_fma(hs, wB, acc23);
            }
            {
                const f32x2 wA = *reinterpret_cast<const f32x2*>(W2 + (j + 1) * 4);
                const f32x2 wB = *reinterpret_cast<const f32x2*>(W2 + (j + 1) * 4 + 2);
                const f32x2 hs = splat_hi(h01);
                acc01 = __builtin_elementwise_fma(hs, wA, acc01);
                acc23 = __builtin_elementwise_fma(hs, wB, acc23);
            }
            {
                const f32x2 wA = *reinterpret_cast<const f32x2*>(W2 + (j + 2) * 4);
                const f32x2 wB = *reinterpret_cast<const f32x2*>(W2 + (j + 2) * 4 + 2);
                const f32x2 hs = splat_lo(h23);
                acc01 = __builtin_elementwise_fma(hs, wA, acc01);
                acc23 = __builtin_elementwise_fma(hs, wB, acc23);
            }
            {
                const f32x2 wA = *reinterpret_cast<const f32x2*>(W2 + (j + 3) * 4);
                const f32x2 wB = *reinterpret_cast<const f32x2*>(W2 + (j + 3) * 4 + 2);
                const f32x2 hs = splat_hi(h23);
                acc01 = __builtin_elementwise_fma(hs, wA, acc01);
                acc23 = __builtin_elementwise_fma(hs, wB, acc23);
            }
        }
        rr = fsigmoid(acc01.x); gg = fsigmoid(acc01.y);
        bb_ = fsigmoid(acc23.x); sg = acc23.y;
    };

    // ---------------- coarse pass ----------------
    const float uc = u_coarse[ray * 64 + lane];
    const float zsc = (float)lane * 0.015625f + uc * 0.015625f;  // bit-match ref
    const float zc = nearv * (1.0f - zsc) + farv * zsc;

    const float zcn = __shfl_down(zc, 1);
    const float deltac = (lane == 63) ? (farv - zc) : (zcn - zc);

    float cr_, cg_, cb_, csig;
    mlp(zc, cr_, cg_, cb_, csig);
    const float alphac = 1.0f - __expf(-deltac * fmaxf(csig, 0.0f));
    const float sc = 1.0f - alphac + 1e-10f;

    // exclusive prefix product -> transmittance (DPP inclusive scan + shift)
    const float pincl = scan_mul(sc);
    float Tc = __shfl_up(pincl, 1);
    if (lane == 0) Tc = 1.0f;
    const float wc = alphac * Tc;

    // coarse outputs: DPP reduce, totals land in lane 63
    const float rc = scan_add(wc * cr_);
    const float gc = scan_add(wc * cg_);
    const float bc = scan_add(wc * cb_);
    const float dc = scan_add(wc * zc);

    // ---------------- fine sampling (inverse CDF, unnormalized) ----------------
    const float wp = wc + 1e-5f;
    const float cdf = scan_add(wp);  // inclusive prefix sum
    const float tot = __int_as_float(__builtin_amdgcn_readlane(__float_as_int(cdf), 63));

    const float uf = u_fine[ray * 64 + lane] * tot;  // compare in unnormalized space
    // inds = #{k: cdf_incl[k] <= u} == searchsorted_right(cdf0, u) - 1, clamped
    int cnt = 0;
#pragma unroll
    for (int step = 64; step >= 1; step >>= 1) {
        const int idx = cnt + step - 1;
        const float v = __shfl(cdf, idx < 64 ? idx : 63);
        if (idx < 64 && v <= uf) cnt += step;
    }
    const float uj = u_jitter[ray * 64 + lane];
    const float zsf = ((float)cnt + uj) * 0.015625f;
    float zf = nearv * (1.0f - zsf) + farv * zsf;

    // ---------------- sort fine z (bitonic, 64 lanes; DPP for j=1,2) ----------------
#pragma unroll
    for (int k = 2; k <= 64; k <<= 1) {
#pragma unroll
        for (int j = k >> 1; j > 0; j >>= 1) {
            float v;
            if (j == 1)      v = dpp_f<0xB1, 0xf>(zf, zf);  // quad_perm [1,0,3,2]
            else if (j == 2) v = dpp_f<0x4E, 0xf>(zf, zf);  // quad_perm [2,3,0,1]
            else             v = __shfl_xor(zf, j);
            const bool keepMin = (((lane & j) == 0) == ((lane & k) == 0));
            zf = keepMin ? fminf(zf, v) : fmaxf(zf, v);
        }
    }

    // fine MLP on sorted fine z (coarse outputs reused, not recomputed)
    float fr_, fg_, fb_, fsig;
    mlp(zf, fr_, fg_, fb_, fsig);

    // ---------------- merge by rank ----------------
    // coarse element: pos = lane + #{fine < zc}  (strict: stable tie order)
    int cf = 0;
#pragma unroll
    for (int step = 64; step >= 1; step >>= 1) {
        const int idx = cf + step - 1;
        const float v = __shfl(zf, idx < 64 ? idx : 63);
        if (idx < 64 && v < zc) cf += step;
    }
    // fine element: pos = lane + #{coarse <= zf}
    int cc = 0;
#pragma unroll
    for (int step = 64; step >= 1; step >>= 1) {
        const int idx = cc + step - 1;
        const float v = __shfl(zc, idx < 64 ? idx : 63);
        if (idx < 64 && v <= zf) cc += step;
    }
    {
        const int pc = lane + cf;
        const int pf = lane + cc;
        mS[wv][0][pc] = zc;   mS[wv][0][pf] = zf;
        mS[wv][1][pc] = cr_;  mS[wv][1][pf] = fr_;
        mS[wv][2][pc] = cg_;  mS[wv][2][pf] = fg_;
        mS[wv][3][pc] = cb_;  mS[wv][3][pf] = fb_;
        mS[wv][4][pc] = csig; mS[wv][4][pf] = fsig;
    }
    __syncthreads();

    // ---------------- fine composite (2 samples / lane) ----------------
    const float2 zz2 = *reinterpret_cast<const float2*>(&mS[wv][0][2 * lane]);
    const float z0 = zz2.x, z1 = zz2.y;
    const float z2n = mS[wv][0][(2 * lane + 2) & 127];
    const float2 rr2 = *reinterpret_cast<const float2*>(&mS[wv][1][2 * lane]);
    const float2 gg2 = *reinterpret_cast<const float2*>(&mS[wv][2][2 * lane]);
    const float2 bb2 = *reinterpret_cast<const float2*>(&mS[wv][3][2 * lane]);
    const float2 ss2 = *reinterpret_cast<const float2*>(&mS[wv][4][2 * lane]);

    const float d0 = z1 - z0;
    const float d1 = (lane == 63) ? (farv - z1) : (z2n - z1);

    const float al0 = 1.0f - __expf(-d0 * fmaxf(ss2.x, 0.0f));
    const float al1 = 1.0f - __expf(-d1 * fmaxf(ss2.y, 0.0f));
    const float t0 = 1.0f - al0 + 1e-10f;
    const float t1 = 1.0f - al1 + 1e-10f;

    // pair product, DPP inclusive scan, exclusive via shift
    const float ppincl = scan_mul(t0 * t1);
    float Te = __shfl_up(ppincl, 1);
    if (lane == 0) Te = 1.0f;
    const float w0 = al0 * Te;
    const float w1 = al1 * (Te * t0);

    // fine outputs: DPP reduce to lane 63
    const float fr = scan_add(fmaf(w0, rr2.x, w1 * rr2.y));
    const float fg = scan_add(fmaf(w0, gg2.x, w1 * gg2.y));
    const float fb = scan_add(fmaf(w0, bb2.x, w1 * bb2.y));
    const float fd = scan_add(fmaf(w0, z0, w1 * z1));

    if (lane == 63) {
        float4* op = reinterpret_cast<float4*>(out + ray * 8);
        op[0] = make_float4(fr, fg, fb, fd);
        op[1] = make_float4(rc, gc, bc, dc);
    }
}

extern "C" void kernel_launch(void* const* d_in, const int* in_sizes, int n_in,
                              void* d_out, int out_size, void* d_ws, size_t ws_size,
                              hipStream_t stream) {
    const float* rays     = (const float*)d_in[0];
    const float* u_coarse = (const float*)d_in[1];
    const float* u_fine   = (const float*)d_in[2];
    const float* u_jitter = (const float*)d_in[3];
    const float* W1       = (const float*)d_in[4];
    const float* b1       = (const float*)d_in[5];
    const float* W2       = (const float*)d_in[6];
    const float* b2       = (const float*)d_in[7];
    float* out = (float*)d_out;

    const int B = in_sizes[0] / 8;          // 65536
    dim3 grid(B / 4), block(256);           // one wave per ray, 4 waves/block
    hipLaunchKernelGGL(nerf_render, grid, block, 0, stream,
                       rays, u_coarse, u_fine, u_jitter, W1, b1, W2, b2, out);
}